// Round 3
// baseline (85.976 us; speedup 1.0000x reference)
//
#include <hip/hip_runtime.h>
#include <hip/hip_bf16.h>

// SpectralInverse: out[b,p,o] = sum_f cos(2*pi*(y[p]·y_w[f] + y_b[f])) * G[b,f,o] + u_b[o]
// where G[b,f,o] = (sum_m h[b,f,m] * u_w[o,m]) / n_grid   (sin(x)~=x folding, err ~1e-10)
// Shapes: B=4, F=128, Cin=64, Cout=8, D=3, NPTS=48^3=110592 per batch.
//
// R3: k0 loop NOT unrolled (R2's full 32x unroll hoisted ~128 VGPRs of w reads
// -> spill theory). Packed f32x2 FMA for Y (v_pk_fma_f32). A-fragment layout
// row=lane&15, k=quad*8+j (verified R1/R2 pass).

#define NPTS      110592
#define NFREQ     128
#define CIN       64
#define COUT      8
#define PTS_BLK   256                 // points per block (4 waves x 64 pts)
#define BLK_PER_B (NPTS / PTS_BLK)    // 432
#define GT_STRIDE 136                 // bf16 elems; breaks pow2 bank stride

typedef __bf16 bf16x8 __attribute__((ext_vector_type(8)));
typedef float  f32x4  __attribute__((ext_vector_type(4)));
typedef float  f32x2  __attribute__((ext_vector_type(2)));

// ---------------------------------------------------------------------------
// Kernel 1: G[b][n][f] (o-major, n padded to 16 with zeros) bf16 into ws,
// plus packed freq params pk[f] = (w0,w1,w2,yb) float4.
// ---------------------------------------------------------------------------
__global__ __launch_bounds__(256) void spectral_prep(
    const float* __restrict__ h,      // (4,128,64)
    const float* __restrict__ u_w,    // (8,64)
    const float* __restrict__ y_w,    // (128,3)
    const float* __restrict__ y_b,    // (128,)
    __bf16* __restrict__ gws,         // (4,16,128)
    float4* __restrict__ pkws)        // (128,)
{
    int b  = blockIdx.x >> 3;
    int fg = blockIdx.x & 7;
    int t  = threadIdx.x;
    int f  = fg * 16 + (t >> 4);
    int n  = t & 15;

    float acc = 0.0f;
    if (n < COUT) {
        const float4* hp = (const float4*)(h + ((size_t)(b * NFREQ + f)) * CIN);
        const float4* up = (const float4*)(u_w + (size_t)n * CIN);
#pragma unroll
        for (int m = 0; m < CIN / 4; ++m) {
            float4 a = hp[m], c = up[m];
            acc += a.x * c.x + a.y * c.y + a.z * c.z + a.w * c.w;
        }
        acc *= (1.0f / (float)NPTS);
    }
    gws[(size_t)b * (16 * NFREQ) + n * NFREQ + f] = (__bf16)acc;

    if (blockIdx.x == 0 && t < NFREQ) {
        pkws[t] = make_float4(y_w[3 * t], y_w[3 * t + 1], y_w[3 * t + 2], y_b[t]);
    }
}

// ---------------------------------------------------------------------------
// Kernel 2: main. grid = 4*432 = 1728 blocks, 256 threads (4 waves).
// Wave wv: points pbase + wv*64 + rt*16 + (lane&15), rt = 0..3.
// ---------------------------------------------------------------------------
__global__ __launch_bounds__(256, 4) void spectral_main(
    const float*  __restrict__ y,     // (4,110592,3)
    const __bf16* __restrict__ gws,   // (4,16,128)
    const float4* __restrict__ pkws,  // (128,)
    const float*  __restrict__ u_b,   // (8,)
    float*        __restrict__ out)   // (4,110592,8)
{
    __shared__ __align__(16) __bf16 GT_lds[16 * GT_STRIDE];   // 4352 B
    __shared__ __align__(16) float4 pk_lds[NFREQ];            // 2048 B
    __shared__ __align__(16) float  y_lds[PTS_BLK * 3];       // 3072 B

    const int t     = threadIdx.x;
    const int b     = blockIdx.x / BLK_PER_B;
    const int pbase = (blockIdx.x % BLK_PER_B) * PTS_BLK;

    // ---- staging (coalesced, once per block) ----
    {
        bf16x8 g = ((const bf16x8*)(gws + (size_t)b * (16 * NFREQ)))[t];
        *(bf16x8*)&GT_lds[(t >> 4) * GT_STRIDE + (t & 15) * 8] = g;
        if (t < NFREQ) pk_lds[t] = pkws[t];
        if (t < PTS_BLK * 3 / 4)
            ((float4*)y_lds)[t] = ((const float4*)(y + ((size_t)b * NPTS + pbase) * 3))[t];
    }
    __syncthreads();

    const int lane = t & 63;
    const int wv   = t >> 6;
    const int quad = lane >> 4;
    const int l15  = lane & 15;

    // y coords for this thread's 4 points, paired for v_pk_fma_f32:
    // pair A = (rt0, rt1), pair B = (rt2, rt3)
    f32x2 y0a, y1a, y2a, y0b, y1b, y2b;
    {
        int p0 = wv * 64 + 0 * 16 + l15;
        int p1 = wv * 64 + 1 * 16 + l15;
        int p2 = wv * 64 + 2 * 16 + l15;
        int p3 = wv * 64 + 3 * 16 + l15;
        y0a = (f32x2){y_lds[p0 * 3 + 0], y_lds[p1 * 3 + 0]};
        y1a = (f32x2){y_lds[p0 * 3 + 1], y_lds[p1 * 3 + 1]};
        y2a = (f32x2){y_lds[p0 * 3 + 2], y_lds[p1 * 3 + 2]};
        y0b = (f32x2){y_lds[p2 * 3 + 0], y_lds[p3 * 3 + 0]};
        y1b = (f32x2){y_lds[p2 * 3 + 1], y_lds[p3 * 3 + 1]};
        y2b = (f32x2){y_lds[p2 * 3 + 2], y_lds[p3 * 3 + 2]};
    }

    f32x4 acc[4] = {{0,0,0,0},{0,0,0,0},{0,0,0,0},{0,0,0,0}};
    const __bf16* bptr = &GT_lds[l15 * GT_STRIDE + quad * 8];
    const float4* wp   = &pk_lds[quad * 8];

#pragma clang loop unroll(disable)
    for (int k0 = 0; k0 < NFREQ; k0 += 32) {
        bf16x8 a0, a1, a2, a3;
#pragma unroll
        for (int j = 0; j < 8; ++j) {
            float4 w = wp[k0 + j];
            f32x2 wx = {w.x, w.x}, wy = {w.y, w.y}, wz = {w.z, w.z}, wb = {w.w, w.w};
            f32x2 Ya = __builtin_elementwise_fma(wx, y0a,
                       __builtin_elementwise_fma(wy, y1a,
                       __builtin_elementwise_fma(wz, y2a, wb)));
            f32x2 Yb = __builtin_elementwise_fma(wx, y0b,
                       __builtin_elementwise_fma(wy, y1b,
                       __builtin_elementwise_fma(wz, y2b, wb)));
            // cos(2*pi*Y): v_cos takes revolutions; v_fract is exact range reduction
            a0[j] = (__bf16)__builtin_amdgcn_cosf(__builtin_amdgcn_fractf(Ya[0]));
            a1[j] = (__bf16)__builtin_amdgcn_cosf(__builtin_amdgcn_fractf(Ya[1]));
            a2[j] = (__bf16)__builtin_amdgcn_cosf(__builtin_amdgcn_fractf(Yb[0]));
            a3[j] = (__bf16)__builtin_amdgcn_cosf(__builtin_amdgcn_fractf(Yb[1]));
        }
        bf16x8 bf = *(const bf16x8*)(bptr + k0);
        acc[0] = __builtin_amdgcn_mfma_f32_16x16x32_bf16(a0, bf, acc[0], 0, 0, 0);
        acc[1] = __builtin_amdgcn_mfma_f32_16x16x32_bf16(a1, bf, acc[1], 0, 0, 0);
        acc[2] = __builtin_amdgcn_mfma_f32_16x16x32_bf16(a2, bf, acc[2], 0, 0, 0);
        acc[3] = __builtin_amdgcn_mfma_f32_16x16x32_bf16(a3, bf, acc[3], 0, 0, 0);
    }

    // ---- epilogue: C/D layout col=lane&15, row=quad*4+reg (verified R1/R2) ----
    if (l15 < COUT) {
        float ub = u_b[l15];
        size_t base = ((size_t)b * NPTS + pbase) * COUT;
#pragma unroll
        for (int rt = 0; rt < 4; ++rt) {
#pragma unroll
            for (int q = 0; q < 4; ++q) {
                int pr = wv * 64 + rt * 16 + quad * 4 + q;
                out[base + (size_t)pr * COUT + l15] = acc[rt][q] + ub;
            }
        }
    }
}

// ---------------------------------------------------------------------------
extern "C" void kernel_launch(void* const* d_in, const int* in_sizes, int n_in,
                              void* d_out, int out_size, void* d_ws, size_t ws_size,
                              hipStream_t stream)
{
    const float* h   = (const float*)d_in[0];
    const float* y   = (const float*)d_in[1];
    const float* y_w = (const float*)d_in[2];
    const float* y_b = (const float*)d_in[3];
    const float* u_w = (const float*)d_in[4];
    const float* u_b = (const float*)d_in[5];
    float* out = (float*)d_out;
    __bf16* gws  = (__bf16*)d_ws;                       // 16 KB
    float4* pkws = (float4*)((char*)d_ws + 16384);      //  2 KB

    spectral_prep<<<32, 256, 0, stream>>>(h, u_w, y_w, y_b, gws, pkws);
    spectral_main<<<4 * BLK_PER_B, 256, 0, stream>>>(y, gws, pkws, u_b, out);
}